// Round 11
// baseline (110.177 us; speedup 1.0000x reference)
//
#include <hip/hip_runtime.h>

// Problem constants: B=16, NEG=128, S=128, D=512, N_PRED=12
#define DIM 512
#define M_ROWS 2048      // B*S

typedef __attribute__((ext_vector_type(8))) short short8;   // 8 bf16 (4 VGPRs)
typedef __attribute__((ext_vector_type(4))) float f32x4;

// f32 -> bf16 round-to-nearest-even (inputs are well-scaled, no NaN expected)
static __device__ __forceinline__ short f2bf(float x) {
    unsigned int u = __builtin_bit_cast(unsigned int, x);
    u += 0x7fffu + ((u >> 16) & 1u);
    return (short)(u >> 16);
}

// ---------------- Kernel 1: c_proj = c @ W[k]^T + b[k], bf16 MFMA ----------------
// (unchanged from R3 — ~5 us, verified)
#define K1_PAD 40
__global__ __launch_bounds__(256) void cproj_mfma(
    const float* __restrict__ c, const float* __restrict__ W,
    const float* __restrict__ bias, const int* __restrict__ kptr,
    float* __restrict__ cp) {
    const int ksel = kptr[0];
    const float* __restrict__ Wk = W + (size_t)ksel * DIM * DIM;
    const float* __restrict__ bk = bias + (size_t)ksel * DIM;

    __shared__ short Alds[64][K1_PAD];
    __shared__ short Blds[64][K1_PAD];

    const int bm = blockIdx.x & 31;
    const int bn = blockIdx.x >> 5;
    const int t  = threadIdx.x;
    const int lane = t & 63;
    const int wv   = t >> 6;

    const int srow = t >> 2;
    const int sk   = (t & 3) * 8;

    const float* Ap = c  + (size_t)(bm * 64 + srow) * DIM + sk;
    const float* Bp = Wk + (size_t)(bn * 64 + srow) * DIM + sk;

    float4 a0 = *(const float4*)Ap,       a1 = *(const float4*)(Ap + 4);
    float4 b0 = *(const float4*)Bp,       b1 = *(const float4*)(Bp + 4);

    f32x4 acc[4] = {};

    const int frow = lane & 15;
    const int fk   = (lane >> 4) * 8;

    for (int step = 0; step < 16; ++step) {
        __syncthreads();
        short8 av, bv;
        av[0] = f2bf(a0.x); av[1] = f2bf(a0.y); av[2] = f2bf(a0.z); av[3] = f2bf(a0.w);
        av[4] = f2bf(a1.x); av[5] = f2bf(a1.y); av[6] = f2bf(a1.z); av[7] = f2bf(a1.w);
        bv[0] = f2bf(b0.x); bv[1] = f2bf(b0.y); bv[2] = f2bf(b0.z); bv[3] = f2bf(b0.w);
        bv[4] = f2bf(b1.x); bv[5] = f2bf(b1.y); bv[6] = f2bf(b1.z); bv[7] = f2bf(b1.w);
        *(short8*)&Alds[srow][sk] = av;
        *(short8*)&Blds[srow][sk] = bv;
        __syncthreads();
        if (step < 15) {
            const int off = (step + 1) * 32;
            a0 = *(const float4*)(Ap + off); a1 = *(const float4*)(Ap + off + 4);
            b0 = *(const float4*)(Bp + off); b1 = *(const float4*)(Bp + off + 4);
        }
        const short8 bfrag = *(const short8*)&Blds[wv * 16 + frow][fk];
#pragma unroll
        for (int f = 0; f < 4; ++f) {
            const short8 afrag = *(const short8*)&Alds[f * 16 + frow][fk];
            acc[f] = __builtin_amdgcn_mfma_f32_16x16x32_bf16(afrag, bfrag, acc[f], 0, 0, 0);
        }
    }

    const int col = bn * 64 + wv * 16 + frow;
    const float bias_v = bk[col];
    const int r0 = (lane >> 4) * 4;
#pragma unroll
    for (int f = 0; f < 4; ++f)
#pragma unroll
        for (int r = 0; r < 4; ++r)
            cp[(size_t)(bm * 64 + f * 16 + r0 + r) * DIM + col] = acc[f][r] + bias_v;
}

// ---------------- Kernel 2: out[b,n,s] = (1/512) * dot(cp[b,s,:], z[b,n,s,:]) ----
// R9 max-injection structure (16384 one-shot blocks, all loads in prologue)
// with ONE change: STREAM-ORDERED dispatch. blk = (b*8+noct)*128 + s, so the
// 128 consecutive blocks of one (b,noct) group read CONTIGUOUS 2 KB chunks of
// the same 16 n-rows — the in-flight request population forms ~16 sequential
// 256 KB streams per group (DRAM page-friendly) instead of scattered 2 KB
// chunks at 256 KB stride (one row-activate each).
#define NS ((size_t)128 * 512)         // n-stride in z (floats)
#define LD4(p) (*(const float4*)(p))

__global__ __launch_bounds__(256) void dot_kernel(
    const float* __restrict__ z, const float* __restrict__ cp,
    float* __restrict__ out) {
    const int blk  = blockIdx.x;             // 0..16383
    const int sid  = blk >> 7;               // stream group = b*8 + noct (0..127)
    const int s    = blk & 127;              // s varies fastest across blocks
    const int b    = sid >> 3;
    const int noct = sid & 7;
    const int bs   = b * 128 + s;
    const int wave = threadIdx.x >> 6;       // 0..3
    const int lane = threadIdx.x & 63;

    // cp row -> registers, contiguous 1 KB halves (L1/L2-broadcast)
    const float* cpr = cp + (size_t)bs * DIM + lane * 4;
    const float4 c0 = LD4(cpr);
    const float4 c1 = LD4(cpr + 256);

    // wave's 4 n's: n = noct*16 + wave*4 + i, i = 0..3
    const int nbase = noct * 16 + wave * 4;
    const float* zp = z + (((size_t)(b * 128 + nbase)) * 128 + s) * DIM + lane * 4;
    float* outp = out + ((size_t)(b * 128 + nbase)) * 128 + s;

    // prologue: all 4 slots issued (8 z loads + 2 cp loads in flight)
    const float4 zA0 = LD4(zp + 0 * NS), zA1 = LD4(zp + 0 * NS + 256);
    const float4 zB0 = LD4(zp + 1 * NS), zB1 = LD4(zp + 1 * NS + 256);
    const float4 zC0 = LD4(zp + 2 * NS), zC1 = LD4(zp + 2 * NS + 256);
    const float4 zD0 = LD4(zp + 3 * NS), zD1 = LD4(zp + 3 * NS + 256);

#define SLOT(Z0, Z1, II)                                                      \
    {                                                                          \
        float acc = Z0.x * c0.x;                                               \
        acc = fmaf(Z0.y, c0.y, acc);                                           \
        acc = fmaf(Z0.z, c0.z, acc);                                           \
        acc = fmaf(Z0.w, c0.w, acc);                                           \
        acc = fmaf(Z1.x, c1.x, acc);                                           \
        acc = fmaf(Z1.y, c1.y, acc);                                           \
        acc = fmaf(Z1.z, c1.z, acc);                                           \
        acc = fmaf(Z1.w, c1.w, acc);                                           \
        _Pragma("unroll")                                                      \
        for (int off = 32; off; off >>= 1) acc += __shfl_xor(acc, off);        \
        if (lane == 0) outp[(size_t)(II) * 128] = acc * (1.0f / 512.0f);       \
    }

    SLOT(zA0, zA1, 0)
    SLOT(zB0, zB1, 1)
    SLOT(zC0, zC1, 2)
    SLOT(zD0, zD1, 3)
#undef SLOT
}

extern "C" void kernel_launch(void* const* d_in, const int* in_sizes, int n_in,
                              void* d_out, int out_size, void* d_ws, size_t ws_size,
                              hipStream_t stream) {
    const float* c    = (const float*)d_in[0];
    const float* z    = (const float*)d_in[1];
    const float* W    = (const float*)d_in[2];
    const float* bias = (const float*)d_in[3];
    const int*   kptr = (const int*)d_in[4];
    float* out = (float*)d_out;
    float* cp  = (float*)d_ws;   // 2048*512*4 = 4 MB scratch for c_proj

    // Kernel 1: 32 M-tiles x 8 N-tiles = 256 blocks, bf16 MFMA
    cproj_mfma<<<dim3(256), dim3(256), 0, stream>>>(c, W, bias, kptr, cp);
    // Kernel 2: 16384 one-shot blocks, stream-ordered dispatch
    dot_kernel<<<dim3(16384), dim3(256), 0, stream>>>(z, cp, out);
}

// Round 12
// 109.514 us; speedup vs baseline: 1.0061x; 1.0061x over previous
//
#include <hip/hip_runtime.h>

// Problem constants: B=16, NEG=128, S=128, D=512, N_PRED=12
#define DIM 512
#define M_ROWS 2048      // B*S

typedef __attribute__((ext_vector_type(8))) short short8;   // 8 bf16 (4 VGPRs)
typedef __attribute__((ext_vector_type(4))) float f32x4;

// f32 -> bf16 round-to-nearest-even (inputs are well-scaled, no NaN expected)
static __device__ __forceinline__ short f2bf(float x) {
    unsigned int u = __builtin_bit_cast(unsigned int, x);
    u += 0x7fffu + ((u >> 16) & 1u);
    return (short)(u >> 16);
}

// ---------------- Kernel 1: c_proj = c @ W[k]^T + b[k], bf16 MFMA ----------------
// (unchanged from R3 — ~5 us, verified)
#define K1_PAD 40
__global__ __launch_bounds__(256) void cproj_mfma(
    const float* __restrict__ c, const float* __restrict__ W,
    const float* __restrict__ bias, const int* __restrict__ kptr,
    float* __restrict__ cp) {
    const int ksel = kptr[0];
    const float* __restrict__ Wk = W + (size_t)ksel * DIM * DIM;
    const float* __restrict__ bk = bias + (size_t)ksel * DIM;

    __shared__ short Alds[64][K1_PAD];
    __shared__ short Blds[64][K1_PAD];

    const int bm = blockIdx.x & 31;
    const int bn = blockIdx.x >> 5;
    const int t  = threadIdx.x;
    const int lane = t & 63;
    const int wv   = t >> 6;

    const int srow = t >> 2;
    const int sk   = (t & 3) * 8;

    const float* Ap = c  + (size_t)(bm * 64 + srow) * DIM + sk;
    const float* Bp = Wk + (size_t)(bn * 64 + srow) * DIM + sk;

    float4 a0 = *(const float4*)Ap,       a1 = *(const float4*)(Ap + 4);
    float4 b0 = *(const float4*)Bp,       b1 = *(const float4*)(Bp + 4);

    f32x4 acc[4] = {};

    const int frow = lane & 15;
    const int fk   = (lane >> 4) * 8;

    for (int step = 0; step < 16; ++step) {
        __syncthreads();
        short8 av, bv;
        av[0] = f2bf(a0.x); av[1] = f2bf(a0.y); av[2] = f2bf(a0.z); av[3] = f2bf(a0.w);
        av[4] = f2bf(a1.x); av[5] = f2bf(a1.y); av[6] = f2bf(a1.z); av[7] = f2bf(a1.w);
        bv[0] = f2bf(b0.x); bv[1] = f2bf(b0.y); bv[2] = f2bf(b0.z); bv[3] = f2bf(b0.w);
        bv[4] = f2bf(b1.x); bv[5] = f2bf(b1.y); bv[6] = f2bf(b1.z); bv[7] = f2bf(b1.w);
        *(short8*)&Alds[srow][sk] = av;
        *(short8*)&Blds[srow][sk] = bv;
        __syncthreads();
        if (step < 15) {
            const int off = (step + 1) * 32;
            a0 = *(const float4*)(Ap + off); a1 = *(const float4*)(Ap + off + 4);
            b0 = *(const float4*)(Bp + off); b1 = *(const float4*)(Bp + off + 4);
        }
        const short8 bfrag = *(const short8*)&Blds[wv * 16 + frow][fk];
#pragma unroll
        for (int f = 0; f < 4; ++f) {
            const short8 afrag = *(const short8*)&Alds[f * 16 + frow][fk];
            acc[f] = __builtin_amdgcn_mfma_f32_16x16x32_bf16(afrag, bfrag, acc[f], 0, 0, 0);
        }
    }

    const int col = bn * 64 + wv * 16 + frow;
    const float bias_v = bk[col];
    const int r0 = (lane >> 4) * 4;
#pragma unroll
    for (int f = 0; f < 4; ++f)
#pragma unroll
        for (int r = 0; r < 4; ++r)
            cp[(size_t)(bm * 64 + f * 16 + r0 + r) * DIM + col] = acc[f][r] + bias_v;
}

// ---------------- Kernel 2: out[b,n,s] = (1/512) * dot(cp[b,s,:], z[b,n,s,:]) ----
// SEQUENTIAL-BURST one-shot variant. Wave = ONE n x FOUR consecutive s-rows:
// its 8 z loads cover 8 KB of physically contiguous memory, issued
// back-to-back (4x longer guaranteed DRAM bursts than R9's 4n x 256KB-stride).
// Block = 4 consecutive n (one per wave) x one s-quad; the 4 cp rows are the
// SAME for all 4 waves (L1 broadcast). One float4 store per wave.
#define LD4(p) (*(const float4*)(p))

__global__ __launch_bounds__(256) void dot_kernel(
    const float* __restrict__ z, const float* __restrict__ cp,
    float* __restrict__ out) {
    const int blk = blockIdx.x;              // 0..16383
    const int sq  = blk & 31;                // s-quad: s = sq*4 .. +3
    const int n4  = (blk >> 5) & 31;         // n-group of 4
    const int b   = blk >> 10;               // 0..15
    const int wave = threadIdx.x >> 6;       // 0..3
    const int lane = threadIdx.x & 63;
    const int n  = n4 * 4 + wave;
    const int s0 = sq * 4;

    // z: 4 consecutive s-rows of (b,n) -> 8 KB contiguous, 8 back-to-back loads
    const float* zp = z + (((size_t)(b * 128 + n)) * 128 + s0) * DIM + lane * 4;
    const float4 zA0 = LD4(zp + 0 * DIM), zA1 = LD4(zp + 0 * DIM + 256);
    const float4 zB0 = LD4(zp + 1 * DIM), zB1 = LD4(zp + 1 * DIM + 256);
    const float4 zC0 = LD4(zp + 2 * DIM), zC1 = LD4(zp + 2 * DIM + 256);
    const float4 zD0 = LD4(zp + 3 * DIM), zD1 = LD4(zp + 3 * DIM + 256);

    // cp: rows s0..s0+3 — identical addresses across the block's 4 waves
    const float* cpr = cp + ((size_t)b * 128 + s0) * DIM + lane * 4;
    const float4 cA0 = LD4(cpr + 0 * DIM), cA1 = LD4(cpr + 0 * DIM + 256);
    const float4 cB0 = LD4(cpr + 1 * DIM), cB1 = LD4(cpr + 1 * DIM + 256);
    const float4 cC0 = LD4(cpr + 2 * DIM), cC1 = LD4(cpr + 2 * DIM + 256);
    const float4 cD0 = LD4(cpr + 3 * DIM), cD1 = LD4(cpr + 3 * DIM + 256);

#define DOT(Z0, Z1, C0, C1, R)                                                \
    {                                                                          \
        float acc = Z0.x * C0.x;                                               \
        acc = fmaf(Z0.y, C0.y, acc);                                           \
        acc = fmaf(Z0.z, C0.z, acc);                                           \
        acc = fmaf(Z0.w, C0.w, acc);                                           \
        acc = fmaf(Z1.x, C1.x, acc);                                           \
        acc = fmaf(Z1.y, C1.y, acc);                                           \
        acc = fmaf(Z1.z, C1.z, acc);                                           \
        acc = fmaf(Z1.w, C1.w, acc);                                           \
        _Pragma("unroll")                                                      \
        for (int off = 32; off; off >>= 1) acc += __shfl_xor(acc, off);        \
        R = acc * (1.0f / 512.0f);                                             \
    }

    float r0, r1, r2, r3;
    DOT(zA0, zA1, cA0, cA1, r0)
    DOT(zB0, zB1, cB0, cB1, r1)
    DOT(zC0, zC1, cC0, cC1, r2)
    DOT(zD0, zD1, cD0, cD1, r3)
#undef DOT

    if (lane == 0) {
        float4 o4;
        o4.x = r0; o4.y = r1; o4.z = r2; o4.w = r3;
        *(float4*)(out + ((size_t)(b * 128 + n)) * 128 + s0) = o4;
    }
}

extern "C" void kernel_launch(void* const* d_in, const int* in_sizes, int n_in,
                              void* d_out, int out_size, void* d_ws, size_t ws_size,
                              hipStream_t stream) {
    const float* c    = (const float*)d_in[0];
    const float* z    = (const float*)d_in[1];
    const float* W    = (const float*)d_in[2];
    const float* bias = (const float*)d_in[3];
    const int*   kptr = (const int*)d_in[4];
    float* out = (float*)d_out;
    float* cp  = (float*)d_ws;   // 2048*512*4 = 4 MB scratch for c_proj

    // Kernel 1: 32 M-tiles x 8 N-tiles = 256 blocks, bf16 MFMA
    cproj_mfma<<<dim3(256), dim3(256), 0, stream>>>(c, W, bias, kptr, cp);
    // Kernel 2: 16384 one-shot blocks; wave = 1 n x 4 consecutive s (8 KB seq)
    dot_kernel<<<dim3(16384), dim3(256), 0, stream>>>(z, cp, out);
}

// Round 14
// 99.141 us; speedup vs baseline: 1.1113x; 1.1046x over previous
//
#include <hip/hip_runtime.h>

// Problem constants: B=16, NEG=128, S=128, D=512, N_PRED=12
#define DIM 512
#define M_ROWS 2048      // B*S

typedef __attribute__((ext_vector_type(8))) short short8;   // 8 bf16 (4 VGPRs)
typedef __attribute__((ext_vector_type(4))) float f32x4;

// f32 -> bf16 round-to-nearest-even (inputs are well-scaled, no NaN expected)
static __device__ __forceinline__ short f2bf(float x) {
    unsigned int u = __builtin_bit_cast(unsigned int, x);
    u += 0x7fffu + ((u >> 16) & 1u);
    return (short)(u >> 16);
}

// ---------------- Kernel 1: c_proj = c @ W[k]^T + b[k], bf16 MFMA ----------------
// (unchanged from R3 — ~5 us, verified)
#define K1_PAD 40
__global__ __launch_bounds__(256) void cproj_mfma(
    const float* __restrict__ c, const float* __restrict__ W,
    const float* __restrict__ bias, const int* __restrict__ kptr,
    float* __restrict__ cp) {
    const int ksel = kptr[0];
    const float* __restrict__ Wk = W + (size_t)ksel * DIM * DIM;
    const float* __restrict__ bk = bias + (size_t)ksel * DIM;

    __shared__ short Alds[64][K1_PAD];
    __shared__ short Blds[64][K1_PAD];

    const int bm = blockIdx.x & 31;
    const int bn = blockIdx.x >> 5;
    const int t  = threadIdx.x;
    const int lane = t & 63;
    const int wv   = t >> 6;

    const int srow = t >> 2;
    const int sk   = (t & 3) * 8;

    const float* Ap = c  + (size_t)(bm * 64 + srow) * DIM + sk;
    const float* Bp = Wk + (size_t)(bn * 64 + srow) * DIM + sk;

    float4 a0 = *(const float4*)Ap,       a1 = *(const float4*)(Ap + 4);
    float4 b0 = *(const float4*)Bp,       b1 = *(const float4*)(Bp + 4);

    f32x4 acc[4] = {};

    const int frow = lane & 15;
    const int fk   = (lane >> 4) * 8;

    for (int step = 0; step < 16; ++step) {
        __syncthreads();
        short8 av, bv;
        av[0] = f2bf(a0.x); av[1] = f2bf(a0.y); av[2] = f2bf(a0.z); av[3] = f2bf(a0.w);
        av[4] = f2bf(a1.x); av[5] = f2bf(a1.y); av[6] = f2bf(a1.z); av[7] = f2bf(a1.w);
        bv[0] = f2bf(b0.x); bv[1] = f2bf(b0.y); bv[2] = f2bf(b0.z); bv[3] = f2bf(b0.w);
        bv[4] = f2bf(b1.x); bv[5] = f2bf(b1.y); bv[6] = f2bf(b1.z); bv[7] = f2bf(b1.w);
        *(short8*)&Alds[srow][sk] = av;
        *(short8*)&Blds[srow][sk] = bv;
        __syncthreads();
        if (step < 15) {
            const int off = (step + 1) * 32;
            a0 = *(const float4*)(Ap + off); a1 = *(const float4*)(Ap + off + 4);
            b0 = *(const float4*)(Bp + off); b1 = *(const float4*)(Bp + off + 4);
        }
        const short8 bfrag = *(const short8*)&Blds[wv * 16 + frow][fk];
#pragma unroll
        for (int f = 0; f < 4; ++f) {
            const short8 afrag = *(const short8*)&Alds[f * 16 + frow][fk];
            acc[f] = __builtin_amdgcn_mfma_f32_16x16x32_bf16(afrag, bfrag, acc[f], 0, 0, 0);
        }
    }

    const int col = bn * 64 + wv * 16 + frow;
    const float bias_v = bk[col];
    const int r0 = (lane >> 4) * 4;
#pragma unroll
    for (int f = 0; f < 4; ++f)
#pragma unroll
        for (int r = 0; r < 4; ++r)
            cp[(size_t)(bm * 64 + f * 16 + r0 + r) * DIM + col] = acc[f][r] + bias_v;
}

// ---------------- Kernel 2: out[b,n,s] = (1/512) * dot(cp[b,s,:], z[b,n,s,:]) ----
// EXACT R9 max-injection structure (best: 107.5 us) with ONE change:
// z loads are NON-TEMPORAL (via clang ext-vector f32x4 — HIP float4 is a
// class type the builtin rejects). z is pure streaming (zero reuse); nt skips
// L2/L3 allocation so streaming data doesn't evict cp or burn L2 fill BW.
// cp loads stay temporal (reused 8x across noct blocks).
#define NS ((size_t)128 * 512)         // n-stride in z (floats)
#define LD4(p)   (*(const f32x4*)(p))
#define LD4NT(p) (__builtin_nontemporal_load((const f32x4*)(p)))

__global__ __launch_bounds__(256) void dot_kernel(
    const float* __restrict__ z, const float* __restrict__ cp,
    float* __restrict__ out) {
    const int blk  = blockIdx.x;             // 0..16383
    const int bs   = blk >> 3;               // b*128 + s (0..2047)
    const int noct = blk & 7;                // n-group of 16
    const int wave = threadIdx.x >> 6;       // 0..3
    const int lane = threadIdx.x & 63;
    const int b = bs >> 7;
    const int s = bs & 127;

    // cp row -> registers, contiguous 1 KB halves (temporal: reused across blocks)
    const float* cpr = cp + (size_t)bs * DIM + lane * 4;
    const f32x4 c0 = LD4(cpr);
    const f32x4 c1 = LD4(cpr + 256);

    // wave's 4 n's: n = noct*16 + wave*4 + i, i = 0..3
    const int nbase = noct * 16 + wave * 4;
    const float* zp = z + (((size_t)(b * 128 + nbase)) * 128 + s) * DIM + lane * 4;
    float* outp = out + ((size_t)(b * 128 + nbase)) * 128 + s;

    // prologue: all 4 slots issued non-temporally (8 z + 2 cp loads in flight)
    const f32x4 zA0 = LD4NT(zp + 0 * NS), zA1 = LD4NT(zp + 0 * NS + 256);
    const f32x4 zB0 = LD4NT(zp + 1 * NS), zB1 = LD4NT(zp + 1 * NS + 256);
    const f32x4 zC0 = LD4NT(zp + 2 * NS), zC1 = LD4NT(zp + 2 * NS + 256);
    const f32x4 zD0 = LD4NT(zp + 3 * NS), zD1 = LD4NT(zp + 3 * NS + 256);

#define SLOT(Z0, Z1, II)                                                      \
    {                                                                          \
        float acc = Z0[0] * c0[0];                                             \
        acc = fmaf(Z0[1], c0[1], acc);                                         \
        acc = fmaf(Z0[2], c0[2], acc);                                         \
        acc = fmaf(Z0[3], c0[3], acc);                                         \
        acc = fmaf(Z1[0], c1[0], acc);                                         \
        acc = fmaf(Z1[1], c1[1], acc);                                         \
        acc = fmaf(Z1[2], c1[2], acc);                                         \
        acc = fmaf(Z1[3], c1[3], acc);                                         \
        _Pragma("unroll")                                                      \
        for (int off = 32; off; off >>= 1) acc += __shfl_xor(acc, off);        \
        if (lane == 0) outp[(size_t)(II) * 128] = acc * (1.0f / 512.0f);       \
    }

    SLOT(zA0, zA1, 0)
    SLOT(zB0, zB1, 1)
    SLOT(zC0, zC1, 2)
    SLOT(zD0, zD1, 3)
#undef SLOT
}

extern "C" void kernel_launch(void* const* d_in, const int* in_sizes, int n_in,
                              void* d_out, int out_size, void* d_ws, size_t ws_size,
                              hipStream_t stream) {
    const float* c    = (const float*)d_in[0];
    const float* z    = (const float*)d_in[1];
    const float* W    = (const float*)d_in[2];
    const float* bias = (const float*)d_in[3];
    const int*   kptr = (const int*)d_in[4];
    float* out = (float*)d_out;
    float* cp  = (float*)d_ws;   // 2048*512*4 = 4 MB scratch for c_proj

    // Kernel 1: 32 M-tiles x 8 N-tiles = 256 blocks, bf16 MFMA
    cproj_mfma<<<dim3(256), dim3(256), 0, stream>>>(c, W, bias, kptr, cp);
    // Kernel 2: 16384 one-shot blocks (R9 mapping), z loads non-temporal
    dot_kernel<<<dim3(16384), dim3(256), 0, stream>>>(z, cp, out);
}